// Round 7
// baseline (183.117 us; speedup 1.0000x reference)
//
#include <hip/hip_runtime.h>
#include <hip/hip_bf16.h>

#define BDIM 4
#define NSEQ 4096
#define DHEAD 128
#define SCALE 0.08838834764831845f

typedef __bf16 bf16x8 __attribute__((ext_vector_type(8)));
typedef float f32x4 __attribute__((ext_vector_type(4)));

__device__ __forceinline__ unsigned short f2bf(float f){
    return __builtin_bit_cast(unsigned short, (__bf16)f);
}
__device__ __forceinline__ unsigned long long pack4(float4 u){
    return (unsigned long long)f2bf(u.x)
         | ((unsigned long long)f2bf(u.y) << 16)
         | ((unsigned long long)f2bf(u.z) << 32)
         | ((unsigned long long)f2bf(u.w) << 48);
}

// ---------------------------------------------------------------------------
// Kernel 1: per-row softmax stats (m, l), K-split=4.  (unchanged, proven)
// ---------------------------------------------------------------------------
extern "C" __global__ __launch_bounds__(256, 4)
void attn_stats(const float* __restrict__ K, const float* __restrict__ Q,
                float* __restrict__ pbase, int pstride)
{
    __shared__ __align__(16) char Klds[64 * 256];

    const int bid = blockIdx.x;
    const int ks  = bid & 3;
    const int rt  = (bid >> 2) & 63;
    const int b   = bid >> 8;
    const int tid = threadIdx.x;
    const int lane = tid & 63;
    const int w    = tid >> 6;
    const int g    = lane >> 4;
    const int c    = lane & 15;
    const int rowbase = rt * 64;

    const float* qrow = Q + ((size_t)b * NSEQ + rowbase + w * 16 + c) * DHEAD;
    bf16x8 qf[4];
#pragma unroll
    for (int kk = 0; kk < 4; kk++) {
        const float4* p0 = (const float4*)(qrow + g * 8 + kk * 32);
        float4 u = p0[0], v = p0[1];
        bf16x8 t;
        t[0] = (__bf16)(u.x * SCALE); t[1] = (__bf16)(u.y * SCALE);
        t[2] = (__bf16)(u.z * SCALE); t[3] = (__bf16)(u.w * SCALE);
        t[4] = (__bf16)(v.x * SCALE); t[5] = (__bf16)(v.y * SCALE);
        t[6] = (__bf16)(v.z * SCALE); t[7] = (__bf16)(v.w * SCALE);
        qf[kk] = t;
    }

    float m[4], l[4];
#pragma unroll
    for (int r = 0; r < 4; r++) { m[r] = -1e30f; l[r] = 0.0f; }

    const int f  = tid & 31;
    const int r0 = tid >> 5;

    for (int kt = 0; kt < 16; kt++) {
        const float* ktile = K + ((size_t)b * NSEQ + ks * 1024 + kt * 64) * DHEAD;
#pragma unroll
        for (int i = 0; i < 8; i++) {
            int r = r0 + i * 8;
            float4 u = *(const float4*)(ktile + (size_t)r * DHEAD + f * 4);
            *(unsigned long long*)(Klds + r * 256 + ((f * 8) ^ ((r & 7) << 4))) = pack4(u);
        }
        __syncthreads();

        f32x4 acc[4];
#pragma unroll
        for (int n = 0; n < 4; n++) acc[n] = (f32x4){0.f, 0.f, 0.f, 0.f};
#pragma unroll
        for (int n = 0; n < 4; n++) {
            int row = n * 16 + c;
#pragma unroll
            for (int kk = 0; kk < 4; kk++) {
                bf16x8 kf = *(const bf16x8*)(Klds + row * 256 +
                                ((g * 16 + kk * 64) ^ ((row & 7) << 4)));
                acc[n] = __builtin_amdgcn_mfma_f32_16x16x32_bf16(qf[kk], kf, acc[n], 0, 0, 0);
            }
        }

#pragma unroll
        for (int r = 0; r < 4; r++) {
            float t = fmaxf(fmaxf(acc[0][r], acc[1][r]), fmaxf(acc[2][r], acc[3][r]));
            t = fmaxf(t, __shfl_xor(t, 1));
            t = fmaxf(t, __shfl_xor(t, 2));
            t = fmaxf(t, __shfl_xor(t, 4));
            t = fmaxf(t, __shfl_xor(t, 8));
            float mn = fmaxf(m[r], t);
            float sc = __expf(m[r] - mn);
            float ps = __expf(acc[0][r] - mn) + __expf(acc[1][r] - mn)
                     + __expf(acc[2][r] - mn) + __expf(acc[3][r] - mn);
            ps += __shfl_xor(ps, 1);
            ps += __shfl_xor(ps, 2);
            ps += __shfl_xor(ps, 4);
            ps += __shfl_xor(ps, 8);
            l[r] = l[r] * sc + ps;
            m[r] = mn;
        }
        __syncthreads();
    }

    if (c == 0) {
#pragma unroll
        for (int r = 0; r < 4; r++) {
            size_t row = rowbase + w * 16 + g * 4 + r;
            float* p = pbase + ((size_t)b * NSEQ + row) * pstride + ks * 2;
            p[0] = m[r];
            p[1] = l[r];
        }
    }
}

// ---------------------------------------------------------------------------
// Kernel R: repack K and V into FRAG-MAJOR bf16 images in ws (per 64-key tile,
// 16 KB each), so attn_stream reads MFMA fragments as single coalesced 1KB
// wave loads (base + lane*16) straight into VGPRs.
//  K2 unit (t4,kk,g,c):  K[T*64 + t4*16 + c][g*8 + kk*32 .. +8]  at unit
//       t4*256 + kk*64 + g*16 + c
//  V2 unit (n2,kq,g,c):  V^T[d = n2*16 + c][T*64 + kq*32 + g*8 .. +8]  at unit
//       n2*128 + kq*64 + g*16 + c
// ---------------------------------------------------------------------------
extern "C" __global__ __launch_bounds__(256, 4)
void repack2(const float* __restrict__ K, const float* __restrict__ V,
             char* __restrict__ ws)
{
    const int bid = blockIdx.x;     // 4b * 64T
    const int T = bid & 63;
    const int b = bid >> 6;
    const int tid = threadIdx.x;

    char* Kp = ws + ((size_t)(b * 64 + T) << 14);
    char* Vp = ws + (4u << 20) + ((size_t)(b * 64 + T) << 14);
    const float* Ks = K + ((size_t)b * NSEQ + T * 64) * DHEAD;
    const float* Vs = V + ((size_t)b * NSEQ + T * 64) * DHEAD;

    // K2: 1024 16B units, coalesced-ish float4 reads
#pragma unroll
    for (int i = 0; i < 4; i++) {
        int u = tid + 256 * i;
        int t4 = u >> 8, kk = (u >> 6) & 3, g = (u >> 4) & 3, c = u & 15;
        const float* s = Ks + (size_t)(t4 * 16 + c) * DHEAD + g * 8 + kk * 32;
        float4 a = *(const float4*)s;
        float4 bq = *(const float4*)(s + 4);
        ulonglong2 wv;
        wv.x = pack4(a);
        wv.y = pack4(bq);
        *(ulonglong2*)(Kp + u * 16) = wv;
    }
    // V2: 1024 16B units, gathered transpose (L2-resident scalar reads)
#pragma unroll
    for (int i = 0; i < 4; i++) {
        int u = tid + 256 * i;
        int n2 = u >> 7, kq = (u >> 6) & 1, g = (u >> 4) & 3, c = u & 15;
        int d = n2 * 16 + c;
        int k0 = kq * 32 + g * 8;
        float v0 = Vs[(size_t)(k0 + 0) * DHEAD + d];
        float v1 = Vs[(size_t)(k0 + 1) * DHEAD + d];
        float v2 = Vs[(size_t)(k0 + 2) * DHEAD + d];
        float v3 = Vs[(size_t)(k0 + 3) * DHEAD + d];
        float v4 = Vs[(size_t)(k0 + 4) * DHEAD + d];
        float v5 = Vs[(size_t)(k0 + 5) * DHEAD + d];
        float v6 = Vs[(size_t)(k0 + 6) * DHEAD + d];
        float v7 = Vs[(size_t)(k0 + 7) * DHEAD + d];
        ulonglong2 wv;
        wv.x = (unsigned long long)f2bf(v0)
             | ((unsigned long long)f2bf(v1) << 16)
             | ((unsigned long long)f2bf(v2) << 32)
             | ((unsigned long long)f2bf(v3) << 48);
        wv.y = (unsigned long long)f2bf(v4)
             | ((unsigned long long)f2bf(v5) << 16)
             | ((unsigned long long)f2bf(v6) << 32)
             | ((unsigned long long)f2bf(v7) << 48);
        *(ulonglong2*)(Vp + u * 16) = wv;
    }
}

// ---------------------------------------------------------------------------
// Kernel 2: streaming finalize — NO barriers in the main loop, no K/V LDS.
// grid = b(4) x rt(64) x ks(2) = 512 blocks, 512 threads (8 waves).
// Wave w: kq = w&1 (32-key half of each 64-key tile), qh = w>>1 (16 q-rows).
// K/V fragments load directly from frag-major ws images into VGPRs.
// P cross-lane fix-up via a per-wave 1KB LDS roundtrip (bank-floor swizzled).
// ctx ks-halves combine via atomicAdd on memset-zeroed ctx.
// ---------------------------------------------------------------------------
extern "C" __global__ __launch_bounds__(512, 2)
void attn_stream(const char* __restrict__ ws, const float* __restrict__ Q,
                 float* __restrict__ out)
{
    __shared__ __align__(16) char LDS[32768];
    // main loop: [0,8K) = 8 x 1KB per-wave P buffers
    // epilogue : [0,32K) = 64 q x 128 d f32 reduction overlay

    const int bid = blockIdx.x;
    const int ks  = bid & 1;
    const int rt  = (bid >> 1) & 63;
    const int b   = bid >> 7;
    const int tid = threadIdx.x;
    const int rowbase = rt * 64;
    const int lane = tid & 63;
    const int w    = tid >> 6;
    const int kq   = w & 1;
    const int qh   = w >> 1;
    const int g    = lane >> 4;
    const int c    = lane & 15;

    float* ctxOut = out;
    float* attn   = out + (size_t)BDIM * NSEQ * DHEAD;
    const float* pbase = (const float*)(ws + (8u << 20));

    char* Pw = LDS + w * 1024;
    const int swz = ((c >> 2) & 3) << 1;         // even XOR on 8B units
    const int pwoff0 = c * 64 + (((0 * 4 + g) ^ swz) << 3);
    const int pwoff1 = c * 64 + (((1 * 4 + g) ^ swz) << 3);
    const int proff  = c * 64 + (((2 * g) ^ swz) << 3);

    // ---- prologue: combine K-split partials -> C for q-row (qh*16 + c) ----
    float Cq;
    {
        const float* prow = pbase + ((size_t)b * NSEQ + rowbase + qh * 16 + c) * 8;
        float4 p0 = *(const float4*)prow;
        float4 p1 = *(const float4*)(prow + 4);
        float M = fmaxf(fmaxf(p0.x, p0.z), fmaxf(p1.x, p1.z));
        float L = p0.y * __expf(p0.x - M) + p0.w * __expf(p0.z - M)
                + p1.y * __expf(p1.x - M) + p1.w * __expf(p1.z - M);
        Cq = M + __logf(L);
    }

    // ---- Q fragments (B operand, q = c within qh tile; scale folded) ----
    const float* qrow = Q + ((size_t)b * NSEQ + rowbase + qh * 16 + c) * DHEAD;
    bf16x8 qf[4];
#pragma unroll
    for (int kk = 0; kk < 4; kk++) {
        const float4* p0 = (const float4*)(qrow + g * 8 + kk * 32);
        float4 u = p0[0], v = p0[1];
        bf16x8 tt;
        tt[0] = (__bf16)(u.x * SCALE); tt[1] = (__bf16)(u.y * SCALE);
        tt[2] = (__bf16)(u.z * SCALE); tt[3] = (__bf16)(u.w * SCALE);
        tt[4] = (__bf16)(v.x * SCALE); tt[5] = (__bf16)(v.y * SCALE);
        tt[6] = (__bf16)(v.z * SCALE); tt[7] = (__bf16)(v.w * SCALE);
        qf[kk] = tt;
    }

    f32x4 ctx[8];
#pragma unroll
    for (int n2 = 0; n2 < 8; n2++) ctx[n2] = (f32x4){0.f, 0.f, 0.f, 0.f};

    const int loff = g * 256 + c * 16;           // == lane*16 (coalesced frag)
    const char* Kp = ws + ((size_t)(b * 64 + ks * 32) << 14);
    const char* Vp = ws + (4u << 20) + ((size_t)(b * 64 + ks * 32) << 14);
    float* arowb = attn + ((size_t)b * NSEQ + rowbase + qh * 16 + c) * NSEQ + ks * 2048;

#pragma unroll 2
    for (int kt = 0; kt < 32; kt++) {
        const char* kt_base = Kp + ((size_t)kt << 14);
        const char* vt_base = Vp + ((size_t)kt << 14);

        // ---- load K fragments (2 nt x 4 kk), each a 1KB coalesced wave load ----
        bf16x8 kf[8];
#pragma unroll
        for (int nt = 0; nt < 2; nt++)
#pragma unroll
            for (int kk = 0; kk < 4; kk++)
                kf[nt * 4 + kk] = *(const bf16x8*)(kt_base +
                    (((kq * 2 + nt) * 4 + kk) << 10) + loff);
        // ---- load V fragments (8 n2): unit n2*128 + kq*64 + lane ----
        bf16x8 vf[8];
#pragma unroll
        for (int n2 = 0; n2 < 8; n2++)
            vf[n2] = *(const bf16x8*)(vt_base + ((n2 * 2 + kq) << 10) + loff);

        // ---- S^T = K Q^T ----
        f32x4 sacc[2];
#pragma unroll
        for (int nt = 0; nt < 2; nt++) sacc[nt] = (f32x4){0.f, 0.f, 0.f, 0.f};
        __builtin_amdgcn_s_setprio(1);
#pragma unroll
        for (int nt = 0; nt < 2; nt++)
#pragma unroll
            for (int kk = 0; kk < 4; kk++)
                sacc[nt] = __builtin_amdgcn_mfma_f32_16x16x32_bf16(
                                kf[nt * 4 + kk], qf[kk], sacc[nt], 0, 0, 0);
        __builtin_amdgcn_s_setprio(0);

        // ---- P = exp(s - C): attn float4 stores + P stash in per-wave LDS ----
        float* arow = arowb + kt * 64 + kq * 32;
        float4 pv0, pv1;
        pv0.x = __expf(sacc[0][0] - Cq); pv0.y = __expf(sacc[0][1] - Cq);
        pv0.z = __expf(sacc[0][2] - Cq); pv0.w = __expf(sacc[0][3] - Cq);
        pv1.x = __expf(sacc[1][0] - Cq); pv1.y = __expf(sacc[1][1] - Cq);
        pv1.z = __expf(sacc[1][2] - Cq); pv1.w = __expf(sacc[1][3] - Cq);
        *(float4*)(arow + g * 4)      = pv0;   // keys kq*32 + 0..15
        *(float4*)(arow + 16 + g * 4) = pv1;   // keys kq*32 + 16..31
        *(unsigned long long*)(Pw + pwoff0) = pack4(pv0);
        *(unsigned long long*)(Pw + pwoff1) = pack4(pv1);
        asm volatile("s_waitcnt lgkmcnt(0)" ::: "memory");
        __builtin_amdgcn_sched_barrier(0);

        bf16x8 pf = *(const bf16x8*)(Pw + proff);   // P[q=c][keys g*8..+8]

        // ---- ctx += P V (K = this wave's 32 keys) ----
        __builtin_amdgcn_s_setprio(1);
#pragma unroll
        for (int n2 = 0; n2 < 8; n2++)
            ctx[n2] = __builtin_amdgcn_mfma_f32_16x16x32_bf16(pf, vf[n2], ctx[n2], 0, 0, 0);
        __builtin_amdgcn_s_setprio(0);
    }

    __syncthreads();   // first block-wide sync since launch

    // ---- reduce kq halves in LDS, atomicAdd ks partial to zeroed ctx ----
    float* red = (float*)LDS;    // 64 q x 128 d
    if (kq == 1) {
#pragma unroll
        for (int n2 = 0; n2 < 8; n2++)
#pragma unroll
            for (int r = 0; r < 4; r++)
                red[(qh * 16 + g * 4 + r) * 128 + n2 * 16 + c] = ctx[n2][r];
    }
    __syncthreads();
    if (kq == 0) {
#pragma unroll
        for (int n2 = 0; n2 < 8; n2++)
#pragma unroll
            for (int r = 0; r < 4; r++) {
                size_t row = rowbase + qh * 16 + g * 4 + r;
                float s = ctx[n2][r] + red[(qh * 16 + g * 4 + r) * 128 + n2 * 16 + c];
                atomicAdd(&ctxOut[((size_t)b * NSEQ + row) * DHEAD + n2 * 16 + c], s);
            }
    }
}

// ---------------------------------------------------------------------------
// Fallback finalize (proven R4 kernel; partials live in attn cols 0..7).
// ---------------------------------------------------------------------------
extern "C" __global__ __launch_bounds__(512, 2)
void attn_final_fb(const float* __restrict__ K, const float* __restrict__ Q,
                   const float* __restrict__ V, float* __restrict__ out)
{
    __shared__ __align__(16) char LDS[81920];

    const int bid = blockIdx.x;
    const int rt  = bid & 63;
    const int b   = bid >> 6;
    const int tid = threadIdx.x;
    const int rowbase = rt * 64;
    const int lane = tid & 63;
    const int w    = tid >> 6;
    const int rw   = w & 3;
    const int grp  = w >> 2;
    const int g    = lane >> 4;
    const int c    = lane & 15;
    const int t    = tid & 255;

    float* ctxOut = out;
    float* attn   = out + (size_t)BDIM * NSEQ * DHEAD;

    char* Klds  = LDS + grp * 16384;
    char* Vtlds = LDS + 32768 + grp * 16384;
    char* Plds  = LDS + 65536 + w * 2048;

    float Cq;
    {
        const float* prow = attn + ((size_t)b * NSEQ + rowbase + rw * 16 + c) * NSEQ;
        float4 p0 = *(const float4*)prow;
        float4 p1 = *(const float4*)(prow + 4);
        float M = fmaxf(fmaxf(p0.x, p0.z), fmaxf(p1.x, p1.z));
        float L = p0.y * __expf(p0.x - M) + p0.w * __expf(p0.z - M)
                + p1.y * __expf(p1.x - M) + p1.w * __expf(p1.z - M);
        Cq = M + __logf(L);
    }

    const float* qrow = Q + ((size_t)b * NSEQ + rowbase + rw * 16 + c) * DHEAD;
    bf16x8 qf[4];
#pragma unroll
    for (int kk = 0; kk < 4; kk++) {
        const float4* p0 = (const float4*)(qrow + g * 8 + kk * 32);
        float4 u = p0[0], v = p0[1];
        bf16x8 tt;
        tt[0] = (__bf16)(u.x * SCALE); tt[1] = (__bf16)(u.y * SCALE);
        tt[2] = (__bf16)(u.z * SCALE); tt[3] = (__bf16)(u.w * SCALE);
        tt[4] = (__bf16)(v.x * SCALE); tt[5] = (__bf16)(v.y * SCALE);
        tt[6] = (__bf16)(v.z * SCALE); tt[7] = (__bf16)(v.w * SCALE);
        qf[kk] = tt;
    }

    f32x4 ctx[8];
#pragma unroll
    for (int n2 = 0; n2 < 8; n2++) ctx[n2] = (f32x4){0.f, 0.f, 0.f, 0.f};

    __syncthreads();

    const int fK = t & 31;
    const int rK = t >> 5;
    const int dq = t & 15;
    const int kb = t >> 4;
    const int k0 = kb * 4;
    const int d0 = dq * 2;

    const float* kbase = K + ((size_t)b * NSEQ + grp * 2048) * DHEAD;
    const float* vbase = V + ((size_t)b * NSEQ + grp * 2048) * DHEAD;

    float4 kreg[8];
    float2 vreg[4][4];

#pragma unroll
    for (int i = 0; i < 8; i++)
        kreg[i] = *(const float4*)(kbase + (size_t)(rK + i * 8) * DHEAD + fK * 4);
#pragma unroll
    for (int i = 0; i < 4; i++)
#pragma unroll
        for (int j = 0; j < 4; j++)
            vreg[i][j] = *(const float2*)(vbase + (size_t)(k0 + j) * DHEAD + d0 + 32 * i);

    for (int kt = 0; kt < 32; kt++) {
        __builtin_amdgcn_s_barrier();

#pragma unroll
        for (int i = 0; i < 8; i++) {
            int row = rK + i * 8;
            *(unsigned long long*)(Klds + row * 256 + ((fK * 8) ^ ((row & 7) << 4))) = pack4(kreg[i]);
        }
#pragma unroll
        for (int i = 0; i < 4; i++) {
            int d = d0 + 32 * i;
            unsigned long long rr0 =
                (unsigned long long)f2bf(vreg[i][0].x)
              | ((unsigned long long)f2bf(vreg[i][1].x) << 16)
              | ((unsigned long long)f2bf(vreg[i][2].x) << 32)
              | ((unsigned long long)f2bf(vreg[i][3].x) << 48);
            unsigned long long rr1 =
                (unsigned long long)f2bf(vreg[i][0].y)
              | ((unsigned long long)f2bf(vreg[i][1].y) << 16)
              | ((unsigned long long)f2bf(vreg[i][2].y) << 32)
              | ((unsigned long long)f2bf(vreg[i][3].y) << 48);
            int swz = (d & 7) << 4;
            *(unsigned long long*)(Vtlds + d * 128 + ((k0 * 2) ^ swz)) = rr0;
            *(unsigned long long*)(Vtlds + (d + 1) * 128 + ((k0 * 2) ^ (swz + 16))) = rr1;
        }
        asm volatile("s_waitcnt lgkmcnt(0)" ::: "memory");
        __builtin_amdgcn_s_barrier();

        {
            int kn = (kt + 1) & 31;
            const float* kp = kbase + (size_t)kn * 64 * DHEAD;
            const float* vp = vbase + (size_t)kn * 64 * DHEAD;
#pragma unroll
            for (int i = 0; i < 8; i++)
                kreg[i] = *(const float4*)(kp + (size_t)(rK + i * 8) * DHEAD + fK * 4);
#pragma unroll
            for (int i = 0; i < 4; i++)
#pragma unroll
                for (int j = 0; j < 4; j++)
                    vreg[i][j] = *(const float2*)(vp + (size_t)(k0 + j) * DHEAD + d0 + 32 * i);
        }

        f32x4 sacc[4];
#pragma unroll
        for (int nt = 0; nt < 4; nt++) sacc[nt] = (f32x4){0.f, 0.f, 0.f, 0.f};
        __builtin_amdgcn_s_setprio(1);
#pragma unroll
        for (int nt = 0; nt < 4; nt++) {
            int row = nt * 16 + c;
#pragma unroll
            for (int kk = 0; kk < 4; kk++) {
                bf16x8 kf = *(const bf16x8*)(Klds + row * 256 +
                                ((g * 16 + kk * 64) ^ ((row & 7) << 4)));
                sacc[nt] = __builtin_amdgcn_mfma_f32_16x16x32_bf16(kf, qf[kk], sacc[nt], 0, 0, 0);
            }
        }
        __builtin_amdgcn_s_setprio(0);

        const int col0 = grp * 2048 + kt * 64;
        float* arow = attn + ((size_t)b * NSEQ + rowbase + rw * 16 + c) * NSEQ + col0;
#pragma unroll
        for (int nt = 0; nt < 4; nt++) {
            float4 pv;
            pv.x = __expf(sacc[nt][0] - Cq);
            pv.y = __expf(sacc[nt][1] - Cq);
            pv.z = __expf(sacc[nt][2] - Cq);
            pv.w = __expf(sacc[nt][3] - Cq);
            *(float4*)(arow + nt * 16 + g * 4) = pv;
            *(unsigned long long*)(Plds + c * 128 +
                ((nt * 32 + g * 8) ^ ((c & 7) << 4))) = pack4(pv);
        }
        asm volatile("s_waitcnt lgkmcnt(0)" ::: "memory");
        __builtin_amdgcn_sched_barrier(0);

        bf16x8 pf[2];
#pragma unroll
        for (int kk = 0; kk < 2; kk++)
            pf[kk] = *(const bf16x8*)(Plds + c * 128 +
                        ((kk * 64 + g * 16) ^ ((c & 7) << 4)));

        __builtin_amdgcn_s_setprio(1);
#pragma unroll
        for (int n2 = 0; n2 < 8; n2++) {
            int d = n2 * 16 + c;
#pragma unroll
            for (int kk = 0; kk < 2; kk++) {
                bf16x8 vff = *(const bf16x8*)(Vtlds + d * 128 +
                                ((kk * 64 + g * 16) ^ ((d & 7) << 4)));
                ctx[n2] = __builtin_amdgcn_mfma_f32_16x16x32_bf16(pf[kk], vff, ctx[n2], 0, 0, 0);
            }
        }
        __builtin_amdgcn_s_setprio(0);
    }

    __syncthreads();

    float* red = (float*)LDS;
    if (grp == 1) {
#pragma unroll
        for (int n2 = 0; n2 < 8; n2++)
#pragma unroll
            for (int r = 0; r < 4; r++)
                red[(rw * 16 + g * 4 + r) * 128 + n2 * 16 + c] = ctx[n2][r];
    }
    __syncthreads();
    if (grp == 0) {
#pragma unroll
        for (int n2 = 0; n2 < 8; n2++)
#pragma unroll
            for (int r = 0; r < 4; r++) {
                size_t row = rowbase + rw * 16 + g * 4 + r;
                ctxOut[((size_t)b * NSEQ + row) * DHEAD + n2 * 16 + c] =
                    ctx[n2][r] + red[(rw * 16 + g * 4 + r) * 128 + n2 * 16 + c];
            }
    }
}

extern "C" void kernel_launch(void* const* d_in, const int* in_sizes, int n_in,
                              void* d_out, int out_size, void* d_ws, size_t ws_size,
                              hipStream_t stream)
{
    const float* K = (const float*)d_in[0];   // "key"
    const float* Q = (const float*)d_in[1];   // "query"
    const float* V = (const float*)d_in[2];   // "value"
    float* out  = (float*)d_out;
    float* attn = out + (size_t)BDIM * NSEQ * DHEAD;

    const size_t need = (8u << 20) + (size_t)BDIM * NSEQ * 8 * sizeof(float);
    if (ws_size >= need) {
        char* ws = (char*)d_ws;
        float* pb = (float*)(ws + (8u << 20));
        hipMemsetAsync(out, 0, (size_t)BDIM * NSEQ * DHEAD * sizeof(float), stream);
        attn_stats<<<dim3(4 * 64 * 4), dim3(256), 0, stream>>>(K, Q, pb, 8);
        repack2<<<dim3(4 * 64), dim3(256), 0, stream>>>(K, V, ws);
        attn_stream<<<dim3(4 * 64 * 2), dim3(512), 0, stream>>>(ws, Q, out);
    } else {
        attn_stats<<<dim3(4 * 64 * 4), dim3(256), 0, stream>>>(K, Q, attn, NSEQ);
        attn_final_fb<<<dim3(4 * 64), dim3(512), 0, stream>>>(K, Q, V, out);
    }
}

// Round 8
// 176.394 us; speedup vs baseline: 1.0381x; 1.0381x over previous
//
#include <hip/hip_runtime.h>
#include <hip/hip_bf16.h>

#define BDIM 4
#define NSEQ 4096
#define DHEAD 128
#define SCALE 0.08838834764831845f

typedef __bf16 bf16x8 __attribute__((ext_vector_type(8)));
typedef float f32x4 __attribute__((ext_vector_type(4)));
typedef float f32x16 __attribute__((ext_vector_type(16)));
typedef unsigned int u32x4 __attribute__((ext_vector_type(4)));

__device__ __forceinline__ unsigned short f2bf(float f){
    return __builtin_bit_cast(unsigned short, (__bf16)f);
}
__device__ __forceinline__ unsigned long long pack4(float4 u){
    return (unsigned long long)f2bf(u.x)
         | ((unsigned long long)f2bf(u.y) << 16)
         | ((unsigned long long)f2bf(u.z) << 32)
         | ((unsigned long long)f2bf(u.w) << 48);
}
__device__ __forceinline__ void gload_lds16(const void* g, void* l){
    __builtin_amdgcn_global_load_lds(
        (const __attribute__((address_space(1))) unsigned int*)g,
        (__attribute__((address_space(3))) unsigned int*)l, 16, 0, 0);
}

// ---------------------------------------------------------------------------
// Kernel 1: per-row softmax stats (m, l), K-split=4.  (unchanged, proven)
// ---------------------------------------------------------------------------
extern "C" __global__ __launch_bounds__(256, 4)
void attn_stats(const float* __restrict__ K, const float* __restrict__ Q,
                float* __restrict__ pbase, int pstride)
{
    __shared__ __align__(16) char Klds[64 * 256];

    const int bid = blockIdx.x;
    const int ks  = bid & 3;
    const int rt  = (bid >> 2) & 63;
    const int b   = bid >> 8;
    const int tid = threadIdx.x;
    const int lane = tid & 63;
    const int w    = tid >> 6;
    const int g    = lane >> 4;
    const int c    = lane & 15;
    const int rowbase = rt * 64;

    const float* qrow = Q + ((size_t)b * NSEQ + rowbase + w * 16 + c) * DHEAD;
    bf16x8 qf[4];
#pragma unroll
    for (int kk = 0; kk < 4; kk++) {
        const float4* p0 = (const float4*)(qrow + g * 8 + kk * 32);
        float4 u = p0[0], v = p0[1];
        bf16x8 t;
        t[0] = (__bf16)(u.x * SCALE); t[1] = (__bf16)(u.y * SCALE);
        t[2] = (__bf16)(u.z * SCALE); t[3] = (__bf16)(u.w * SCALE);
        t[4] = (__bf16)(v.x * SCALE); t[5] = (__bf16)(v.y * SCALE);
        t[6] = (__bf16)(v.z * SCALE); t[7] = (__bf16)(v.w * SCALE);
        qf[kk] = t;
    }

    float m[4], l[4];
#pragma unroll
    for (int r = 0; r < 4; r++) { m[r] = -1e30f; l[r] = 0.0f; }

    const int f  = tid & 31;
    const int r0 = tid >> 5;

    for (int kt = 0; kt < 16; kt++) {
        const float* ktile = K + ((size_t)b * NSEQ + ks * 1024 + kt * 64) * DHEAD;
#pragma unroll
        for (int i = 0; i < 8; i++) {
            int r = r0 + i * 8;
            float4 u = *(const float4*)(ktile + (size_t)r * DHEAD + f * 4);
            *(unsigned long long*)(Klds + r * 256 + ((f * 8) ^ ((r & 7) << 4))) = pack4(u);
        }
        __syncthreads();

        f32x4 acc[4];
#pragma unroll
        for (int n = 0; n < 4; n++) acc[n] = (f32x4){0.f, 0.f, 0.f, 0.f};
#pragma unroll
        for (int n = 0; n < 4; n++) {
            int row = n * 16 + c;
#pragma unroll
            for (int kk = 0; kk < 4; kk++) {
                bf16x8 kf = *(const bf16x8*)(Klds + row * 256 +
                                ((g * 16 + kk * 64) ^ ((row & 7) << 4)));
                acc[n] = __builtin_amdgcn_mfma_f32_16x16x32_bf16(qf[kk], kf, acc[n], 0, 0, 0);
            }
        }

#pragma unroll
        for (int r = 0; r < 4; r++) {
            float t = fmaxf(fmaxf(acc[0][r], acc[1][r]), fmaxf(acc[2][r], acc[3][r]));
            t = fmaxf(t, __shfl_xor(t, 1));
            t = fmaxf(t, __shfl_xor(t, 2));
            t = fmaxf(t, __shfl_xor(t, 4));
            t = fmaxf(t, __shfl_xor(t, 8));
            float mn = fmaxf(m[r], t);
            float sc = __expf(m[r] - mn);
            float ps = __expf(acc[0][r] - mn) + __expf(acc[1][r] - mn)
                     + __expf(acc[2][r] - mn) + __expf(acc[3][r] - mn);
            ps += __shfl_xor(ps, 1);
            ps += __shfl_xor(ps, 2);
            ps += __shfl_xor(ps, 4);
            ps += __shfl_xor(ps, 8);
            l[r] = l[r] * sc + ps;
            m[r] = mn;
        }
        __syncthreads();
    }

    if (c == 0) {
#pragma unroll
        for (int r = 0; r < 4; r++) {
            size_t row = rowbase + w * 16 + g * 4 + r;
            float* p = pbase + ((size_t)b * NSEQ + row) * pstride + ks * 2;
            p[0] = m[r];
            p[1] = l[r];
        }
    }
}

// ---------------------------------------------------------------------------
// Kernel R: repack K,V into frag-major images for mfma_f32_32x32x16_bf16.
// Per 32-key tile (4b x 128T): 16KB = K frags (8KB) + V^T frags (8KB).
//  K unit u (0..511):  ds=u>>6, lane=u&63, hi=lane>>5, m=lane&31:
//     K[T*32+m][ds*16 + hi*8 .. +8]                  @ Kp + u*16
//  V unit u (0..511):  f=u>>6 (dg=f>>1, kb=f&1), lane: dd=lane&31, hi:
//     V^T[d=dg*32+dd][T*32 + kb*16 + hi*8 .. +8]     @ Kp + 8192 + u*16
// ---------------------------------------------------------------------------
extern "C" __global__ __launch_bounds__(256, 4)
void repack3(const float* __restrict__ K, const float* __restrict__ V,
             char* __restrict__ ws)
{
    const int bid = blockIdx.x;     // 4b * 128T
    const int T = bid & 127;
    const int b = bid >> 7;
    const int tid = threadIdx.x;

    char* Kp = ws + ((size_t)(b * 128 + T) << 14);
    const float* Ks = K + ((size_t)b * NSEQ + T * 32) * DHEAD;
    const float* Vs = V + ((size_t)b * NSEQ + T * 32) * DHEAD;

    // K: 512 units, 2 per thread
#pragma unroll
    for (int i = 0; i < 2; i++) {
        int u = tid + 256 * i;
        int ds = u >> 6, ln = u & 63;
        int m = ln & 31, hi = ln >> 5;
        const float* s = Ks + (size_t)m * DHEAD + ds * 16 + hi * 8;
        float4 a = *(const float4*)s;
        float4 bq = *(const float4*)(s + 4);
        ulonglong2 wv;
        wv.x = pack4(a);
        wv.y = pack4(bq);
        *(ulonglong2*)(Kp + u * 16) = wv;
    }
    // V^T: 512 units, 2 per thread (gathered transpose)
#pragma unroll
    for (int i = 0; i < 2; i++) {
        int u = tid + 256 * i;
        int f = u >> 6, ln = u & 63;
        int dg = f >> 1, kb = f & 1;
        int dd = ln & 31, hi = ln >> 5;
        int d = dg * 32 + dd;
        const float* s = Vs + (size_t)(kb * 16 + hi * 8) * DHEAD + d;
        float v0 = s[0 * DHEAD], v1 = s[1 * DHEAD], v2 = s[2 * DHEAD], v3 = s[3 * DHEAD];
        float v4 = s[4 * DHEAD], v5 = s[5 * DHEAD], v6 = s[6 * DHEAD], v7 = s[7 * DHEAD];
        ulonglong2 wv;
        wv.x = (unsigned long long)f2bf(v0)
             | ((unsigned long long)f2bf(v1) << 16)
             | ((unsigned long long)f2bf(v2) << 32)
             | ((unsigned long long)f2bf(v3) << 48);
        wv.y = (unsigned long long)f2bf(v4)
             | ((unsigned long long)f2bf(v5) << 16)
             | ((unsigned long long)f2bf(v6) << 32)
             | ((unsigned long long)f2bf(v7) << 48);
        *(ulonglong2*)(Kp + 8192 + u * 16) = wv;
    }
}

// ---------------------------------------------------------------------------
// Kernel 2: finalize with 32x32x16 MFMA (2x arithmetic intensity).
// grid = ks(4) x qt(32) x b(4) = 512 blocks, 256 thr (4 waves).
// Wave wv: 32 q rows (q = qt*128 + wv*32 + (lane&31)); block: ks quarter of
// keys = 32 tiles of 32 keys.  LDS dbuf 2x16KB, gload_lds + counted vmcnt(4).
// Softmax per-lane scalar (q = lane&31); P rebuilt in-register for PV via
// 8 packs + 8 shfl_xor(32) + cndmask.  ctx partials -> ws (reduce kernel) or
// atomicAdd fallback.
// ---------------------------------------------------------------------------
extern "C" __global__ __launch_bounds__(256, 2)
void attn_mf(const char* __restrict__ ws, const float* __restrict__ Q,
             float* __restrict__ out, float* __restrict__ part, int use_atomic)
{
    __shared__ __align__(16) char LDS[32768];

    const int bid = blockIdx.x;
    const int ks  = bid & 3;
    const int qt  = (bid >> 2) & 31;
    const int b   = bid >> 7;
    const int tid = threadIdx.x;
    const int wv  = tid >> 6;
    const int lane = tid & 63;
    const int hi   = lane >> 5;
    const int qq   = lane & 31;
    const int q    = qt * 128 + wv * 32 + qq;   // global q row within batch b

    float* attn = out + (size_t)BDIM * NSEQ * DHEAD;
    const float* pb = (const float*)(ws + (8u << 20));

    // ---- prologue: combine K-split partials -> C = M + log(L), per lane ----
    float Cq;
    {
        const float* prow = pb + ((size_t)b * NSEQ + q) * 8;
        float4 p0 = *(const float4*)prow;
        float4 p1 = *(const float4*)(prow + 4);
        float M = fmaxf(fmaxf(p0.x, p0.z), fmaxf(p1.x, p1.z));
        float L = p0.y * __expf(p0.x - M) + p0.w * __expf(p0.z - M)
                + p1.y * __expf(p1.x - M) + p1.w * __expf(p1.z - M);
        Cq = M + __logf(L);
    }

    // ---- Q fragments (B operand: n=q=lane&31, k=ds*16+hi*8+e), SCALE folded ----
    const float* qrow = Q + ((size_t)b * NSEQ + q) * DHEAD;
    bf16x8 qf[8];
#pragma unroll
    for (int ds = 0; ds < 8; ds++) {
        const float4* p0 = (const float4*)(qrow + ds * 16 + hi * 8);
        float4 u = p0[0], v = p0[1];
        bf16x8 t;
        t[0] = (__bf16)(u.x * SCALE); t[1] = (__bf16)(u.y * SCALE);
        t[2] = (__bf16)(u.z * SCALE); t[3] = (__bf16)(u.w * SCALE);
        t[4] = (__bf16)(v.x * SCALE); t[5] = (__bf16)(v.y * SCALE);
        t[6] = (__bf16)(v.z * SCALE); t[7] = (__bf16)(v.w * SCALE);
        qf[ds] = t;
    }

    f32x16 ctx[4];
#pragma unroll
    for (int dg = 0; dg < 4; dg++) ctx[dg] = (f32x16)(0.0f);

    const char* img = ws + ((size_t)(b * 128 + ks * 32) << 14);

    // ---- prologue stage: tile 0 -> buf 0 (4 x 16B per thread) ----
#pragma unroll
    for (int i = 0; i < 4; i++) {
        int o = tid * 16 + i * 4096;
        gload_lds16(img + o, LDS + o);
    }

    float* arowb = attn + ((size_t)b * NSEQ + q) * NSEQ + ks * 1024 + 4 * hi;

    for (int kt = 0; kt < 32; kt++) {
        __builtin_amdgcn_s_barrier();
        __builtin_amdgcn_sched_barrier(0);
        if (kt < 31) {
            const char* src = img + ((size_t)(kt + 1) << 14);
            char* dst = LDS + (((kt + 1) & 1) << 14);
#pragma unroll
            for (int i = 0; i < 4; i++) {
                int o = tid * 16 + i * 4096;
                gload_lds16(src + o, dst + o);
            }
            asm volatile("s_waitcnt vmcnt(4)" ::: "memory");
        } else {
            asm volatile("s_waitcnt vmcnt(0)" ::: "memory");
        }
        __builtin_amdgcn_s_barrier();
        __builtin_amdgcn_sched_barrier(0);

        const char* bufc = LDS + ((kt & 1) << 14);

        // ---- S^T = K Q^T : one 32x32 tile, K-chain over 8 d-slices ----
        f32x16 sacc = (f32x16)(0.0f);
        __builtin_amdgcn_s_setprio(1);
#pragma unroll
        for (int ds = 0; ds < 8; ds++) {
            bf16x8 kf = *(const bf16x8*)(bufc + ds * 1024 + lane * 16);
            sacc = __builtin_amdgcn_mfma_f32_32x32x16_bf16(kf, qf[ds], sacc, 0, 0, 0);
        }
        __builtin_amdgcn_s_setprio(0);

        // ---- P = exp(s - C); attn float4 stores ----
        float p[16];
#pragma unroll
        for (int r = 0; r < 16; r++) p[r] = __expf(sacc[r] - Cq);

        float* arow = arowb + kt * 32;
#pragma unroll
        for (int j = 0; j < 4; j++) {
            float4 pv = {p[4 * j], p[4 * j + 1], p[4 * j + 2], p[4 * j + 3]};
            *(float4*)(arow + 8 * j) = pv;
        }

        // ---- rebuild P as PV B-operand in-register (T12 structure) ----
        unsigned int bpk[8], sb[8];
#pragma unroll
        for (int i = 0; i < 8; i++)
            bpk[i] = (unsigned int)f2bf(p[2 * i]) | ((unsigned int)f2bf(p[2 * i + 1]) << 16);
#pragma unroll
        for (int i = 0; i < 8; i++)
            sb[i] = (unsigned int)__shfl_xor((int)bpk[i], 32);

        u32x4 w0, w1;
        w0[0] = hi ? sb[2] : bpk[0];
        w0[1] = hi ? sb[3] : bpk[1];
        w0[2] = hi ? bpk[2] : sb[0];
        w0[3] = hi ? bpk[3] : sb[1];
        w1[0] = hi ? sb[6] : bpk[4];
        w1[1] = hi ? sb[7] : bpk[5];
        w1[2] = hi ? bpk[6] : sb[4];
        w1[3] = hi ? bpk[7] : sb[5];
        bf16x8 pf0 = __builtin_bit_cast(bf16x8, w0);
        bf16x8 pf1 = __builtin_bit_cast(bf16x8, w1);

        // ---- ctx += P V : 4 d-groups x 2 key-halves ----
        __builtin_amdgcn_s_setprio(1);
#pragma unroll
        for (int dg = 0; dg < 4; dg++) {
            bf16x8 vf0 = *(const bf16x8*)(bufc + 8192 + (dg * 2 + 0) * 1024 + lane * 16);
            bf16x8 vf1 = *(const bf16x8*)(bufc + 8192 + (dg * 2 + 1) * 1024 + lane * 16);
            ctx[dg] = __builtin_amdgcn_mfma_f32_32x32x16_bf16(vf0, pf0, ctx[dg], 0, 0, 0);
            ctx[dg] = __builtin_amdgcn_mfma_f32_32x32x16_bf16(vf1, pf1, ctx[dg], 0, 0, 0);
        }
        __builtin_amdgcn_s_setprio(0);
    }

    // ---- epilogue: write ctx partial (d = dg*32 + 8j + 4hi + 0..3) ----
    if (!use_atomic) {
        float* cp = part + (((size_t)(ks * 4 + b) * NSEQ + q) * DHEAD) + 4 * hi;
#pragma unroll
        for (int dg = 0; dg < 4; dg++)
#pragma unroll
            for (int j = 0; j < 4; j++) {
                float4 v = {ctx[dg][4 * j], ctx[dg][4 * j + 1],
                            ctx[dg][4 * j + 2], ctx[dg][4 * j + 3]};
                *(float4*)(cp + dg * 32 + 8 * j) = v;
            }
    } else {
        float* cp = out + ((size_t)b * NSEQ + q) * DHEAD + 4 * hi;
#pragma unroll
        for (int dg = 0; dg < 4; dg++)
#pragma unroll
            for (int j = 0; j < 4; j++)
#pragma unroll
                for (int e = 0; e < 4; e++)
                    atomicAdd(cp + dg * 32 + 8 * j + e, ctx[dg][4 * j + e]);
    }
}

// ---------------------------------------------------------------------------
// Kernel 3: reduce the 4 ks-partials into ctx (deterministic, no atomics).
// ---------------------------------------------------------------------------
extern "C" __global__ __launch_bounds__(256, 4)
void ctx_reduce(const float4* __restrict__ part, float4* __restrict__ out)
{
    const size_t gt = (size_t)blockIdx.x * 256 + threadIdx.x;   // 524288 float4s
    const size_t stride = (size_t)BDIM * NSEQ * DHEAD / 4;      // per-ks stride
    float4 a = part[gt];
    float4 b = part[gt + stride];
    float4 c = part[gt + 2 * stride];
    float4 d = part[gt + 3 * stride];
    float4 s;
    s.x = (a.x + b.x) + (c.x + d.x);
    s.y = (a.y + b.y) + (c.y + d.y);
    s.z = (a.z + b.z) + (c.z + d.z);
    s.w = (a.w + b.w) + (c.w + d.w);
    out[gt] = s;
}

// ---------------------------------------------------------------------------
// Fallback finalize (proven R4 kernel; partials live in attn cols 0..7).
// ---------------------------------------------------------------------------
extern "C" __global__ __launch_bounds__(512, 2)
void attn_final_fb(const float* __restrict__ K, const float* __restrict__ Q,
                   const float* __restrict__ V, float* __restrict__ out)
{
    __shared__ __align__(16) char LDS[81920];

    const int bid = blockIdx.x;
    const int rt  = bid & 63;
    const int b   = bid >> 6;
    const int tid = threadIdx.x;
    const int rowbase = rt * 64;
    const int lane = tid & 63;
    const int w    = tid >> 6;
    const int rw   = w & 3;
    const int grp  = w >> 2;
    const int g    = lane >> 4;
    const int c    = lane & 15;
    const int t    = tid & 255;

    float* ctxOut = out;
    float* attn   = out + (size_t)BDIM * NSEQ * DHEAD;

    char* Klds  = LDS + grp * 16384;
    char* Vtlds = LDS + 32768 + grp * 16384;
    char* Plds  = LDS + 65536 + w * 2048;

    float Cq;
    {
        const float* prow = attn + ((size_t)b * NSEQ + rowbase + rw * 16 + c) * NSEQ;
        float4 p0 = *(const float4*)prow;
        float4 p1 = *(const float4*)(prow + 4);
        float M = fmaxf(fmaxf(p0.x, p0.z), fmaxf(p1.x, p1.z));
        float L = p0.y * __expf(p0.x - M) + p0.w * __expf(p0.z - M)
                + p1.y * __expf(p1.x - M) + p1.w * __expf(p1.z - M);
        Cq = M + __logf(L);
    }

    const float* qrow = Q + ((size_t)b * NSEQ + rowbase + rw * 16 + c) * DHEAD;
    bf16x8 qf[4];
#pragma unroll
    for (int kk = 0; kk < 4; kk++) {
        const float4* p0 = (const float4*)(qrow + g * 8 + kk * 32);
        float4 u = p0[0], v = p0[1];
        bf16x8 tt;
        tt[0] = (__bf16)(u.x * SCALE); tt[1] = (__bf16)(u.y * SCALE);
        tt[2] = (__bf16)(u.z * SCALE); tt[3] = (__bf16)(u.w * SCALE);
        tt[4] = (__bf16)(v.x * SCALE); tt[5] = (__bf16)(v.y * SCALE);
        tt[6] = (__bf16)(v.z * SCALE); tt[7] = (__bf16)(v.w * SCALE);
        qf[kk] = tt;
    }

    f32x4 ctx[8];
#pragma unroll
    for (int n2 = 0; n2 < 8; n2++) ctx[n2] = (f32x4){0.f, 0.f, 0.f, 0.f};

    __syncthreads();

    const int fK = t & 31;
    const int rK = t >> 5;
    const int dq = t & 15;
    const int kb = t >> 4;
    const int k0 = kb * 4;
    const int d0 = dq * 2;

    const float* kbase = K + ((size_t)b * NSEQ + grp * 2048) * DHEAD;
    const float* vbase = V + ((size_t)b * NSEQ + grp * 2048) * DHEAD;

    float4 kreg[8];
    float2 vreg[4][4];

#pragma unroll
    for (int i = 0; i < 8; i++)
        kreg[i] = *(const float4*)(kbase + (size_t)(rK + i * 8) * DHEAD + fK * 4);
#pragma unroll
    for (int i = 0; i < 4; i++)
#pragma unroll
        for (int j = 0; j < 4; j++)
            vreg[i][j] = *(const float2*)(vbase + (size_t)(k0 + j) * DHEAD + d0 + 32 * i);

    for (int kt = 0; kt < 32; kt++) {
        __builtin_amdgcn_s_barrier();

#pragma unroll
        for (int i = 0; i < 8; i++) {
            int row = rK + i * 8;
            *(unsigned long long*)(Klds + row * 256 + ((fK * 8) ^ ((row & 7) << 4))) = pack4(kreg[i]);
        }
#pragma unroll
        for (int i = 0; i < 4; i++) {
            int d = d0 + 32 * i;
            unsigned long long rr0 =
                (unsigned long long)f2bf(vreg[i][0].x)
              | ((unsigned long long)f2bf(vreg[i][1].x) << 16)
              | ((unsigned long long)f2bf(vreg[i][2].x) << 32)
              | ((unsigned long long)f2bf(vreg[i][3].x) << 48);
            unsigned long long rr1 =
                (unsigned long long)f2bf(vreg[i][0].y)
              | ((unsigned long long)f2bf(vreg[i][1].y) << 16)
              | ((unsigned long long)f2bf(vreg[i][2].y) << 32)
              | ((unsigned long long)f2bf(vreg[i][3].y) << 48);
            int swz = (d & 7) << 4;
            *(unsigned long long*)(Vtlds + d * 128 + ((k0 * 2) ^ swz)) = rr0;
            *(unsigned long long*)(Vtlds + (d + 1) * 128 + ((k0 * 2) ^ (swz + 16))) = rr1;
        }
        asm volatile("s_waitcnt lgkmcnt(0)" ::: "memory");
        __builtin_amdgcn_s_barrier();

        {
            int kn = (kt + 1) & 31;
            const float* kp = kbase + (size_t)kn * 64 * DHEAD;
            const float* vp = vbase + (size_t)kn * 64 * DHEAD;
#pragma unroll
            for (int i = 0; i < 8; i++)
                kreg[i] = *(const float4*)(kp + (size_t)(rK + i * 8) * DHEAD + fK * 4);
#pragma unroll
            for (int i = 0; i < 4; i++)
#pragma unroll
                for (int j = 0; j < 4; j++)
                    vreg[i][j] = *(const float2*)(vp + (size_t)(k0 + j) * DHEAD + d0 + 32 * i);
        }

        f32x4 sacc[4];
#pragma unroll
        for (int nt = 0; nt < 4; nt++) sacc[nt] = (f32x4){0.f, 0.f, 0.f, 0.f};
        __builtin_amdgcn_s_setprio(1);
#pragma unroll
        for (int nt = 0; nt < 4; nt++) {
            int row = nt * 16 + c;
#pragma unroll
            for (int kk = 0; kk < 4; kk++) {
                bf16x8 kf = *(const bf16x8*)(Klds + row * 256 +
                                ((g * 16 + kk * 64) ^ ((row & 7) << 4)));
                sacc[nt] = __builtin_amdgcn_mfma_f32_16x16x32_bf16(kf, qf[kk], sacc[nt], 0, 0, 0);
            }
        }
        __builtin_amdgcn_s_setprio(0);

        const int col0 = grp * 2048 + kt * 64;
        float* arow = attn + ((size_t)b * NSEQ + rowbase + rw * 16 + c) * NSEQ + col0;
#pragma unroll
        for (int nt = 0; nt < 4; nt++) {
            float4 pv;
            pv.x = __expf(sacc[nt][0] - Cq);
            pv.y = __expf(sacc[nt][1] - Cq);
            pv.z = __expf(sacc[nt][2] - Cq);
            pv.w = __expf(sacc[nt][3] - Cq);
            *(float4*)(arow + nt * 16 + g * 4) = pv;
            *(unsigned long long*)(Plds + c * 128 +
                ((nt * 32 + g * 8) ^ ((c & 7) << 4))) = pack4(pv);
        }
        asm volatile("s_waitcnt lgkmcnt(0)" ::: "memory");
        __builtin_amdgcn_sched_barrier(0);

        bf16x8 pf[2];
#pragma unroll
        for (int kk = 0; kk < 2; kk++)
            pf[kk] = *(const bf16x8*)(Plds + c * 128 +
                        ((kk * 64 + g * 16) ^ ((c & 7) << 4)));

        __builtin_amdgcn_s_setprio(1);
#pragma unroll
        for (int n2 = 0; n2 < 8; n2++) {
            int d = n2 * 16 + c;
#pragma unroll
            for (int kk = 0; kk < 2; kk++) {
                bf16x8 vff = *(const bf16x8*)(Vtlds + d * 128 +
                                ((kk * 64 + g * 16) ^ ((d & 7) << 4)));
                ctx[n2] = __builtin_amdgcn_mfma_f32_16x16x32_bf16(pf[kk], vff, ctx[n2], 0, 0, 0);
            }
        }
        __builtin_amdgcn_s_setprio(0);
    }

    __syncthreads();

    float* red = (float*)LDS;
    if (grp == 1) {
#pragma unroll
        for (int n2 = 0; n2 < 8; n2++)
#pragma unroll
            for (int r = 0; r < 4; r++)
                red[(rw * 16 + g * 4 + r) * 128 + n2 * 16 + c] = ctx[n2][r];
    }
    __syncthreads();
    if (grp == 0) {
#pragma unroll
        for (int n2 = 0; n2 < 8; n2++)
#pragma unroll
            for (int r = 0; r < 4; r++) {
                size_t row = rowbase + rw * 16 + g * 4 + r;
                ctxOut[((size_t)b * NSEQ + row) * DHEAD + n2 * 16 + c] =
                    ctx[n2][r] + red[(rw * 16 + g * 4 + r) * 128 + n2 * 16 + c];
            }
    }
}

extern "C" void kernel_launch(void* const* d_in, const int* in_sizes, int n_in,
                              void* d_out, int out_size, void* d_ws, size_t ws_size,
                              hipStream_t stream)
{
    const float* K = (const float*)d_in[0];   // "key"
    const float* Q = (const float*)d_in[1];   // "query"
    const float* V = (const float*)d_in[2];   // "value"
    float* out  = (float*)d_out;
    float* attn = out + (size_t)BDIM * NSEQ * DHEAD;

    const size_t ctx_bytes  = (size_t)BDIM * NSEQ * DHEAD * sizeof(float);  // 8 MB
    const size_t need_part  = (9u << 20) + 4 * ctx_bytes;                   // 41 MB
    const size_t need_atom  = (8u << 20) + (size_t)BDIM * NSEQ * 8 * sizeof(float);

    if (ws_size >= need_part) {
        char* ws = (char*)d_ws;
        float* pb = (float*)(ws + (8u << 20));
        float* part = (float*)(ws + (9u << 20));
        attn_stats<<<dim3(4 * 64 * 4), dim3(256), 0, stream>>>(K, Q, pb, 8);
        repack3<<<dim3(4 * 128), dim3(256), 0, stream>>>(K, V, ws);
        attn_mf<<<dim3(512), dim3(256), 0, stream>>>(ws, Q, out, part, 0);
        ctx_reduce<<<dim3(2048), dim3(256), 0, stream>>>((const float4*)part, (float4*)out);
    } else if (ws_size >= need_atom) {
        char* ws = (char*)d_ws;
        float* pb = (float*)(ws + (8u << 20));
        hipMemsetAsync(out, 0, ctx_bytes, stream);
        attn_stats<<<dim3(4 * 64 * 4), dim3(256), 0, stream>>>(K, Q, pb, 8);
        repack3<<<dim3(4 * 128), dim3(256), 0, stream>>>(K, V, ws);
        attn_mf<<<dim3(512), dim3(256), 0, stream>>>(ws, Q, out, out, 1);
    } else {
        attn_stats<<<dim3(4 * 64 * 4), dim3(256), 0, stream>>>(K, Q, attn, NSEQ);
        attn_final_fb<<<dim3(4 * 64), dim3(512), 0, stream>>>(K, Q, V, out);
    }
}

// Round 9
// 162.695 us; speedup vs baseline: 1.1255x; 1.0842x over previous
//
#include <hip/hip_runtime.h>
#include <hip/hip_bf16.h>

#define BDIM 4
#define NSEQ 4096
#define DHEAD 128
#define SCALE 0.08838834764831845f

typedef __bf16 bf16x8 __attribute__((ext_vector_type(8)));
typedef float f32x4 __attribute__((ext_vector_type(4)));
typedef float f32x16 __attribute__((ext_vector_type(16)));
typedef unsigned int u32x4 __attribute__((ext_vector_type(4)));

__device__ __forceinline__ unsigned short f2bf(float f){
    return __builtin_bit_cast(unsigned short, (__bf16)f);
}
__device__ __forceinline__ unsigned long long pack4(float4 u){
    return (unsigned long long)f2bf(u.x)
         | ((unsigned long long)f2bf(u.y) << 16)
         | ((unsigned long long)f2bf(u.z) << 32)
         | ((unsigned long long)f2bf(u.w) << 48);
}
__device__ __forceinline__ void gload_lds16(const void* g, void* l){
    __builtin_amdgcn_global_load_lds(
        (const __attribute__((address_space(1))) unsigned int*)g,
        (__attribute__((address_space(3))) unsigned int*)l, 16, 0, 0);
}

// ---------------------------------------------------------------------------
// Kernel 1: per-row softmax stats (m, l), K-split=4.  (unchanged, proven)
// ---------------------------------------------------------------------------
extern "C" __global__ __launch_bounds__(256, 4)
void attn_stats(const float* __restrict__ K, const float* __restrict__ Q,
                float* __restrict__ pbase, int pstride)
{
    __shared__ __align__(16) char Klds[64 * 256];

    const int bid = blockIdx.x;
    const int ks  = bid & 3;
    const int rt  = (bid >> 2) & 63;
    const int b   = bid >> 8;
    const int tid = threadIdx.x;
    const int lane = tid & 63;
    const int w    = tid >> 6;
    const int g    = lane >> 4;
    const int c    = lane & 15;
    const int rowbase = rt * 64;

    const float* qrow = Q + ((size_t)b * NSEQ + rowbase + w * 16 + c) * DHEAD;
    bf16x8 qf[4];
#pragma unroll
    for (int kk = 0; kk < 4; kk++) {
        const float4* p0 = (const float4*)(qrow + g * 8 + kk * 32);
        float4 u = p0[0], v = p0[1];
        bf16x8 t;
        t[0] = (__bf16)(u.x * SCALE); t[1] = (__bf16)(u.y * SCALE);
        t[2] = (__bf16)(u.z * SCALE); t[3] = (__bf16)(u.w * SCALE);
        t[4] = (__bf16)(v.x * SCALE); t[5] = (__bf16)(v.y * SCALE);
        t[6] = (__bf16)(v.z * SCALE); t[7] = (__bf16)(v.w * SCALE);
        qf[kk] = t;
    }

    float m[4], l[4];
#pragma unroll
    for (int r = 0; r < 4; r++) { m[r] = -1e30f; l[r] = 0.0f; }

    const int f  = tid & 31;
    const int r0 = tid >> 5;

    for (int kt = 0; kt < 16; kt++) {
        const float* ktile = K + ((size_t)b * NSEQ + ks * 1024 + kt * 64) * DHEAD;
#pragma unroll
        for (int i = 0; i < 8; i++) {
            int r = r0 + i * 8;
            float4 u = *(const float4*)(ktile + (size_t)r * DHEAD + f * 4);
            *(unsigned long long*)(Klds + r * 256 + ((f * 8) ^ ((r & 7) << 4))) = pack4(u);
        }
        __syncthreads();

        f32x4 acc[4];
#pragma unroll
        for (int n = 0; n < 4; n++) acc[n] = (f32x4){0.f, 0.f, 0.f, 0.f};
#pragma unroll
        for (int n = 0; n < 4; n++) {
            int row = n * 16 + c;
#pragma unroll
            for (int kk = 0; kk < 4; kk++) {
                bf16x8 kf = *(const bf16x8*)(Klds + row * 256 +
                                ((g * 16 + kk * 64) ^ ((row & 7) << 4)));
                acc[n] = __builtin_amdgcn_mfma_f32_16x16x32_bf16(qf[kk], kf, acc[n], 0, 0, 0);
            }
        }

#pragma unroll
        for (int r = 0; r < 4; r++) {
            float t = fmaxf(fmaxf(acc[0][r], acc[1][r]), fmaxf(acc[2][r], acc[3][r]));
            t = fmaxf(t, __shfl_xor(t, 1));
            t = fmaxf(t, __shfl_xor(t, 2));
            t = fmaxf(t, __shfl_xor(t, 4));
            t = fmaxf(t, __shfl_xor(t, 8));
            float mn = fmaxf(m[r], t);
            float sc = __expf(m[r] - mn);
            float ps = __expf(acc[0][r] - mn) + __expf(acc[1][r] - mn)
                     + __expf(acc[2][r] - mn) + __expf(acc[3][r] - mn);
            ps += __shfl_xor(ps, 1);
            ps += __shfl_xor(ps, 2);
            ps += __shfl_xor(ps, 4);
            ps += __shfl_xor(ps, 8);
            l[r] = l[r] * sc + ps;
            m[r] = mn;
        }
        __syncthreads();
    }

    if (c == 0) {
#pragma unroll
        for (int r = 0; r < 4; r++) {
            size_t row = rowbase + w * 16 + g * 4 + r;
            float* p = pbase + ((size_t)b * NSEQ + row) * pstride + ks * 2;
            p[0] = m[r];
            p[1] = l[r];
        }
    }
}

// ---------------------------------------------------------------------------
// Kernel R: repack K,V into frag-major images for mfma_f32_32x32x16_bf16.
// (unchanged from R8 — verified correct by the passing run)
// ---------------------------------------------------------------------------
extern "C" __global__ __launch_bounds__(256, 4)
void repack3(const float* __restrict__ K, const float* __restrict__ V,
             char* __restrict__ ws)
{
    const int bid = blockIdx.x;     // 4b * 128T
    const int T = bid & 127;
    const int b = bid >> 7;
    const int tid = threadIdx.x;

    char* Kp = ws + ((size_t)(b * 128 + T) << 14);
    const float* Ks = K + ((size_t)b * NSEQ + T * 32) * DHEAD;
    const float* Vs = V + ((size_t)b * NSEQ + T * 32) * DHEAD;

#pragma unroll
    for (int i = 0; i < 2; i++) {
        int u = tid + 256 * i;
        int ds = u >> 6, ln = u & 63;
        int m = ln & 31, hi = ln >> 5;
        const float* s = Ks + (size_t)m * DHEAD + ds * 16 + hi * 8;
        float4 a = *(const float4*)s;
        float4 bq = *(const float4*)(s + 4);
        ulonglong2 wv;
        wv.x = pack4(a);
        wv.y = pack4(bq);
        *(ulonglong2*)(Kp + u * 16) = wv;
    }
#pragma unroll
    for (int i = 0; i < 2; i++) {
        int u = tid + 256 * i;
        int f = u >> 6, ln = u & 63;
        int dg = f >> 1, kb = f & 1;
        int dd = ln & 31, hi = ln >> 5;
        int d = dg * 32 + dd;
        const float* s = Vs + (size_t)(kb * 16 + hi * 8) * DHEAD + d;
        float v0 = s[0 * DHEAD], v1 = s[1 * DHEAD], v2 = s[2 * DHEAD], v3 = s[3 * DHEAD];
        float v4 = s[4 * DHEAD], v5 = s[5 * DHEAD], v6 = s[6 * DHEAD], v7 = s[7 * DHEAD];
        ulonglong2 wv;
        wv.x = (unsigned long long)f2bf(v0)
             | ((unsigned long long)f2bf(v1) << 16)
             | ((unsigned long long)f2bf(v2) << 32)
             | ((unsigned long long)f2bf(v3) << 48);
        wv.y = (unsigned long long)f2bf(v4)
             | ((unsigned long long)f2bf(v5) << 16)
             | ((unsigned long long)f2bf(v6) << 32)
             | ((unsigned long long)f2bf(v7) << 48);
        *(ulonglong2*)(Kp + 8192 + u * 16) = wv;
    }
}

// ---------------------------------------------------------------------------
// Kernel 2: 32x32x16 finalize, occupancy/ILP-fixed.
// grid = ks(8) x qt(32) x b(4) = 1024 blocks, 256 thr (4 waves),
// __launch_bounds__(256,3) -> 3 blocks/CU (LDS 32KB, VGPR<=170).
// Each wave: 32 q rows x 512 keys (16 tiles of 32).  sacc = 2 interleaved
// 4-deep chains; vf loaded lazily (2 live).  In-register P rebuild (verified).
// ---------------------------------------------------------------------------
extern "C" __global__ __launch_bounds__(256, 3)
void attn_mf2(const char* __restrict__ ws, const float* __restrict__ Q,
              float* __restrict__ out, float* __restrict__ part, int use_atomic)
{
    __shared__ __align__(16) char LDS[32768];

    const int bid = blockIdx.x;
    const int ks  = bid & 7;
    const int qt  = (bid >> 3) & 31;
    const int b   = bid >> 8;
    const int tid = threadIdx.x;
    const int wv  = tid >> 6;
    const int lane = tid & 63;
    const int hi   = lane >> 5;
    const int qq   = lane & 31;
    const int q    = qt * 128 + wv * 32 + qq;

    float* attn = out + (size_t)BDIM * NSEQ * DHEAD;
    const float* pb = (const float*)(ws + (8u << 20));

    float Cq;
    {
        const float* prow = pb + ((size_t)b * NSEQ + q) * 8;
        float4 p0 = *(const float4*)prow;
        float4 p1 = *(const float4*)(prow + 4);
        float M = fmaxf(fmaxf(p0.x, p0.z), fmaxf(p1.x, p1.z));
        float L = p0.y * __expf(p0.x - M) + p0.w * __expf(p0.z - M)
                + p1.y * __expf(p1.x - M) + p1.w * __expf(p1.z - M);
        Cq = M + __logf(L);
    }

    const float* qrow = Q + ((size_t)b * NSEQ + q) * DHEAD;
    bf16x8 qf[8];
#pragma unroll
    for (int ds = 0; ds < 8; ds++) {
        const float4* p0 = (const float4*)(qrow + ds * 16 + hi * 8);
        float4 u = p0[0], v = p0[1];
        bf16x8 t;
        t[0] = (__bf16)(u.x * SCALE); t[1] = (__bf16)(u.y * SCALE);
        t[2] = (__bf16)(u.z * SCALE); t[3] = (__bf16)(u.w * SCALE);
        t[4] = (__bf16)(v.x * SCALE); t[5] = (__bf16)(v.y * SCALE);
        t[6] = (__bf16)(v.z * SCALE); t[7] = (__bf16)(v.w * SCALE);
        qf[ds] = t;
    }

    f32x16 ctx[4];
#pragma unroll
    for (int dg = 0; dg < 4; dg++) ctx[dg] = (f32x16)(0.0f);

    const char* img = ws + ((size_t)(b * 128 + ks * 16) << 14);   // 16 tiles

    // prologue: tile 0 -> buf 0
#pragma unroll
    for (int i = 0; i < 4; i++) {
        int o = tid * 16 + i * 4096;
        gload_lds16(img + o, LDS + o);
    }

    float* arowb = attn + ((size_t)b * NSEQ + q) * NSEQ + ks * 512 + 4 * hi;

    for (int kt = 0; kt < 16; kt++) {
        __builtin_amdgcn_s_barrier();
        __builtin_amdgcn_sched_barrier(0);
        if (kt < 15) {
            const char* src = img + ((size_t)(kt + 1) << 14);
            char* dst = LDS + (((kt + 1) & 1) << 14);
#pragma unroll
            for (int i = 0; i < 4; i++) {
                int o = tid * 16 + i * 4096;
                gload_lds16(src + o, dst + o);
            }
            asm volatile("s_waitcnt vmcnt(4)" ::: "memory");
        } else {
            asm volatile("s_waitcnt vmcnt(0)" ::: "memory");
        }
        __builtin_amdgcn_s_barrier();
        __builtin_amdgcn_sched_barrier(0);

        const char* bufc = LDS + ((kt & 1) << 14);

        // ---- S^T = K Q^T : two interleaved 4-deep chains ----
        f32x16 s0 = (f32x16)(0.0f), s1 = (f32x16)(0.0f);
        __builtin_amdgcn_s_setprio(1);
#pragma unroll
        for (int dp = 0; dp < 4; dp++) {
            bf16x8 kfa = *(const bf16x8*)(bufc + (2 * dp) * 1024 + lane * 16);
            bf16x8 kfb = *(const bf16x8*)(bufc + (2 * dp + 1) * 1024 + lane * 16);
            s0 = __builtin_amdgcn_mfma_f32_32x32x16_bf16(kfa, qf[2 * dp], s0, 0, 0, 0);
            s1 = __builtin_amdgcn_mfma_f32_32x32x16_bf16(kfb, qf[2 * dp + 1], s1, 0, 0, 0);
        }
        __builtin_amdgcn_s_setprio(0);

        // ---- P = exp(s - C); attn stores; pack for PV ----
        float p[16];
#pragma unroll
        for (int r = 0; r < 16; r++) p[r] = __expf((s0[r] + s1[r]) - Cq);

        float* arow = arowb + kt * 32;
#pragma unroll
        for (int j = 0; j < 4; j++) {
            float4 pv = {p[4 * j], p[4 * j + 1], p[4 * j + 2], p[4 * j + 3]};
            *(float4*)(arow + 8 * j) = pv;
        }

        unsigned int bpk[8], sb[8];
#pragma unroll
        for (int i = 0; i < 8; i++)
            bpk[i] = (unsigned int)f2bf(p[2 * i]) | ((unsigned int)f2bf(p[2 * i + 1]) << 16);
#pragma unroll
        for (int i = 0; i < 8; i++)
            sb[i] = (unsigned int)__shfl_xor((int)bpk[i], 32);

        u32x4 w0, w1;
        w0[0] = hi ? sb[2] : bpk[0];
        w0[1] = hi ? sb[3] : bpk[1];
        w0[2] = hi ? bpk[2] : sb[0];
        w0[3] = hi ? bpk[3] : sb[1];
        w1[0] = hi ? sb[6] : bpk[4];
        w1[1] = hi ? sb[7] : bpk[5];
        w1[2] = hi ? bpk[6] : sb[4];
        w1[3] = hi ? bpk[7] : sb[5];
        bf16x8 pf0 = __builtin_bit_cast(bf16x8, w0);
        bf16x8 pf1 = __builtin_bit_cast(bf16x8, w1);

        // ---- ctx += P V : lazy vf loads, 4 independent dg chains ----
        __builtin_amdgcn_s_setprio(1);
#pragma unroll
        for (int dg = 0; dg < 4; dg++) {
            bf16x8 vf0 = *(const bf16x8*)(bufc + 8192 + (dg * 2 + 0) * 1024 + lane * 16);
            bf16x8 vf1 = *(const bf16x8*)(bufc + 8192 + (dg * 2 + 1) * 1024 + lane * 16);
            ctx[dg] = __builtin_amdgcn_mfma_f32_32x32x16_bf16(vf0, pf0, ctx[dg], 0, 0, 0);
            ctx[dg] = __builtin_amdgcn_mfma_f32_32x32x16_bf16(vf1, pf1, ctx[dg], 0, 0, 0);
        }
        __builtin_amdgcn_s_setprio(0);
    }

    // ---- epilogue ----
    if (!use_atomic) {
        float* cp = part + (((size_t)(ks * 4 + b) * NSEQ + q) * DHEAD) + 4 * hi;
#pragma unroll
        for (int dg = 0; dg < 4; dg++)
#pragma unroll
            for (int j = 0; j < 4; j++) {
                float4 v = {ctx[dg][4 * j], ctx[dg][4 * j + 1],
                            ctx[dg][4 * j + 2], ctx[dg][4 * j + 3]};
                *(float4*)(cp + dg * 32 + 8 * j) = v;
            }
    } else {
        float* cp = out + ((size_t)b * NSEQ + q) * DHEAD + 4 * hi;
#pragma unroll
        for (int dg = 0; dg < 4; dg++)
#pragma unroll
            for (int j = 0; j < 4; j++)
#pragma unroll
                for (int e = 0; e < 4; e++)
                    atomicAdd(cp + dg * 32 + 8 * j + e, ctx[dg][4 * j + e]);
    }
}

// ---------------------------------------------------------------------------
// Kernel 3: reduce the 8 ks-partials into ctx (deterministic).
// ---------------------------------------------------------------------------
extern "C" __global__ __launch_bounds__(256, 4)
void ctx_reduce8(const float4* __restrict__ part, float4* __restrict__ out)
{
    const size_t gt = (size_t)blockIdx.x * 256 + threadIdx.x;   // 524288 float4s
    const size_t stride = (size_t)BDIM * NSEQ * DHEAD / 4;
    float4 s = part[gt];
#pragma unroll
    for (int i = 1; i < 8; i++) {
        float4 a = part[gt + (size_t)i * stride];
        s.x += a.x; s.y += a.y; s.z += a.z; s.w += a.w;
    }
    out[gt] = s;
}

// ---------------------------------------------------------------------------
// Fallback finalize (proven R4 kernel; partials live in attn cols 0..7).
// ---------------------------------------------------------------------------
extern "C" __global__ __launch_bounds__(512, 2)
void attn_final_fb(const float* __restrict__ K, const float* __restrict__ Q,
                   const float* __restrict__ V, float* __restrict__ out)
{
    __shared__ __align__(16) char LDS[81920];

    const int bid = blockIdx.x;
    const int rt  = bid & 63;
    const int b   = bid >> 6;
    const int tid = threadIdx.x;
    const int rowbase = rt * 64;
    const int lane = tid & 63;
    const int w    = tid >> 6;
    const int rw   = w & 3;
    const int grp  = w >> 2;
    const int g    = lane >> 4;
    const int c    = lane & 15;
    const int t    = tid & 255;

    float* ctxOut = out;
    float* attn   = out + (size_t)BDIM * NSEQ * DHEAD;

    char* Klds  = LDS + grp * 16384;
    char* Vtlds = LDS + 32768 + grp * 16384;
    char* Plds  = LDS + 65536 + w * 2048;

    float Cq;
    {
        const float* prow = attn + ((size_t)b * NSEQ + rowbase + rw * 16 + c) * NSEQ;
        float4 p0 = *(const float4*)prow;
        float4 p1 = *(const float4*)(prow + 4);
        float M = fmaxf(fmaxf(p0.x, p0.z), fmaxf(p1.x, p1.z));
        float L = p0.y * __expf(p0.x - M) + p0.w * __expf(p0.z - M)
                + p1.y * __expf(p1.x - M) + p1.w * __expf(p1.z - M);
        Cq = M + __logf(L);
    }

    const float* qrow = Q + ((size_t)b * NSEQ + rowbase + rw * 16 + c) * DHEAD;
    bf16x8 qf[4];
#pragma unroll
    for (int kk = 0; kk < 4; kk++) {
        const float4* p0 = (const float4*)(qrow + g * 8 + kk * 32);
        float4 u = p0[0], v = p0[1];
        bf16x8 tt;
        tt[0] = (__bf16)(u.x * SCALE); tt[1] = (__bf16)(u.y * SCALE);
        tt[2] = (__bf16)(u.z * SCALE); tt[3] = (__bf16)(u.w * SCALE);
        tt[4] = (__bf16)(v.x * SCALE); tt[5] = (__bf16)(v.y * SCALE);
        tt[6] = (__bf16)(v.z * SCALE); tt[7] = (__bf16)(v.w * SCALE);
        qf[kk] = tt;
    }

    f32x4 ctx[8];
#pragma unroll
    for (int n2 = 0; n2 < 8; n2++) ctx[n2] = (f32x4){0.f, 0.f, 0.f, 0.f};

    __syncthreads();

    const int fK = t & 31;
    const int rK = t >> 5;
    const int dq = t & 15;
    const int kb = t >> 4;
    const int k0 = kb * 4;
    const int d0 = dq * 2;

    const float* kbase = K + ((size_t)b * NSEQ + grp * 2048) * DHEAD;
    const float* vbase = V + ((size_t)b * NSEQ + grp * 2048) * DHEAD;

    float4 kreg[8];
    float2 vreg[4][4];

#pragma unroll
    for (int i = 0; i < 8; i++)
        kreg[i] = *(const float4*)(kbase + (size_t)(rK + i * 8) * DHEAD + fK * 4);
#pragma unroll
    for (int i = 0; i < 4; i++)
#pragma unroll
        for (int j = 0; j < 4; j++)
            vreg[i][j] = *(const float2*)(vbase + (size_t)(k0 + j) * DHEAD + d0 + 32 * i);

    for (int kt = 0; kt < 32; kt++) {
        __builtin_amdgcn_s_barrier();

#pragma unroll
        for (int i = 0; i < 8; i++) {
            int row = rK + i * 8;
            *(unsigned long long*)(Klds + row * 256 + ((fK * 8) ^ ((row & 7) << 4))) = pack4(kreg[i]);
        }
#pragma unroll
        for (int i = 0; i < 4; i++) {
            int d = d0 + 32 * i;
            unsigned long long rr0 =
                (unsigned long long)f2bf(vreg[i][0].x)
              | ((unsigned long long)f2bf(vreg[i][1].x) << 16)
              | ((unsigned long long)f2bf(vreg[i][2].x) << 32)
              | ((unsigned long long)f2bf(vreg[i][3].x) << 48);
            unsigned long long rr1 =
                (unsigned long long)f2bf(vreg[i][0].y)
              | ((unsigned long long)f2bf(vreg[i][1].y) << 16)
              | ((unsigned long long)f2bf(vreg[i][2].y) << 32)
              | ((unsigned long long)f2bf(vreg[i][3].y) << 48);
            int swz = (d & 7) << 4;
            *(unsigned long long*)(Vtlds + d * 128 + ((k0 * 2) ^ swz)) = rr0;
            *(unsigned long long*)(Vtlds + (d + 1) * 128 + ((k0 * 2) ^ (swz + 16))) = rr1;
        }
        asm volatile("s_waitcnt lgkmcnt(0)" ::: "memory");
        __builtin_amdgcn_s_barrier();

        {
            int kn = (kt + 1) & 31;
            const float* kp = kbase + (size_t)kn * 64 * DHEAD;
            const float* vp = vbase + (size_t)kn * 64 * DHEAD;
#pragma unroll
            for (int i = 0; i < 8; i++)
                kreg[i] = *(const float4*)(kp + (size_t)(rK + i * 8) * DHEAD + fK * 4);
#pragma unroll
            for (int i = 0; i < 4; i++)
#pragma unroll
                for (int j = 0; j < 4; j++)
                    vreg[i][j] = *(const float2*)(vp + (size_t)(k0 + j) * DHEAD + d0 + 32 * i);
        }

        f32x4 sacc[4];
#pragma unroll
        for (int nt = 0; nt < 4; nt++) sacc[nt] = (f32x4){0.f, 0.f, 0.f, 0.f};
        __builtin_amdgcn_s_setprio(1);
#pragma unroll
        for (int nt = 0; nt < 4; nt++) {
            int row = nt * 16 + c;
#pragma unroll
            for (int kk = 0; kk < 4; kk++) {
                bf16x8 kf = *(const bf16x8*)(Klds + row * 256 +
                                ((g * 16 + kk * 64) ^ ((row & 7) << 4)));
                sacc[nt] = __builtin_amdgcn_mfma_f32_16x16x32_bf16(kf, qf[kk], sacc[nt], 0, 0, 0);
            }
        }
        __builtin_amdgcn_s_setprio(0);

        const int col0 = grp * 2048 + kt * 64;
        float* arow = attn + ((size_t)b * NSEQ + rowbase + rw * 16 + c) * NSEQ + col0;
#pragma unroll
        for (int nt = 0; nt < 4; nt++) {
            float4 pv;
            pv.x = __expf(sacc[nt][0] - Cq);
            pv.y = __expf(sacc[nt][1] - Cq);
            pv.z = __expf(sacc[nt][2] - Cq);
            pv.w = __expf(sacc[nt][3] - Cq);
            *(float4*)(arow + nt * 16 + g * 4) = pv;
            *(unsigned long long*)(Plds + c * 128 +
                ((nt * 32 + g * 8) ^ ((c & 7) << 4))) = pack4(pv);
        }
        asm volatile("s_waitcnt lgkmcnt(0)" ::: "memory");
        __builtin_amdgcn_sched_barrier(0);

        bf16x8 pf[2];
#pragma unroll
        for (int kk = 0; kk < 2; kk++)
            pf[kk] = *(const bf16x8*)(Plds + c * 128 +
                        ((kk * 64 + g * 16) ^ ((c & 7) << 4)));

        __builtin_amdgcn_s_setprio(1);
#pragma unroll
        for (int n2 = 0; n2 < 8; n2++) {
            int d = n2 * 16 + c;
#pragma unroll
            for (int kk = 0; kk < 2; kk++) {
                bf16x8 vff = *(const bf16x8*)(Vtlds + d * 128 +
                                ((kk * 64 + g * 16) ^ ((d & 7) << 4)));
                ctx[n2] = __builtin_amdgcn_mfma_f32_16x16x32_bf16(pf[kk], vff, ctx[n2], 0, 0, 0);
            }
        }
        __builtin_amdgcn_s_setprio(0);
    }

    __syncthreads();

    float* red = (float*)LDS;
    if (grp == 1) {
#pragma unroll
        for (int n2 = 0; n2 < 8; n2++)
#pragma unroll
            for (int r = 0; r < 4; r++)
                red[(rw * 16 + g * 4 + r) * 128 + n2 * 16 + c] = ctx[n2][r];
    }
    __syncthreads();
    if (grp == 0) {
#pragma unroll
        for (int n2 = 0; n2 < 8; n2++)
#pragma unroll
            for (int r = 0; r < 4; r++) {
                size_t row = rowbase + rw * 16 + g * 4 + r;
                ctxOut[((size_t)b * NSEQ + row) * DHEAD + n2 * 16 + c] =
                    ctx[n2][r] + red[(rw * 16 + g * 4 + r) * 128 + n2 * 16 + c];
            }
    }
}

extern "C" void kernel_launch(void* const* d_in, const int* in_sizes, int n_in,
                              void* d_out, int out_size, void* d_ws, size_t ws_size,
                              hipStream_t stream)
{
    const float* K = (const float*)d_in[0];   // "key"
    const float* Q = (const float*)d_in[1];   // "query"
    const float* V = (const float*)d_in[2];   // "value"
    float* out  = (float*)d_out;
    float* attn = out + (size_t)BDIM * NSEQ * DHEAD;

    const size_t ctx_bytes  = (size_t)BDIM * NSEQ * DHEAD * sizeof(float);  // 8 MB
    const size_t need_part  = (9u << 20) + 8 * ctx_bytes;                   // 73 MB
    const size_t need_atom  = (9u << 20);

    if (ws_size >= need_part) {
        char* ws = (char*)d_ws;
        float* pb = (float*)(ws + (8u << 20));
        float* part = (float*)(ws + (9u << 20));
        attn_stats<<<dim3(4 * 64 * 4), dim3(256), 0, stream>>>(K, Q, pb, 8);
        repack3<<<dim3(4 * 128), dim3(256), 0, stream>>>(K, V, ws);
        attn_mf2<<<dim3(1024), dim3(256), 0, stream>>>(ws, Q, out, part, 0);
        ctx_reduce8<<<dim3(2048), dim3(256), 0, stream>>>((const float4*)part, (float4*)out);
    } else if (ws_size >= need_atom) {
        char* ws = (char*)d_ws;
        float* pb = (float*)(ws + (8u << 20));
        hipMemsetAsync(out, 0, ctx_bytes, stream);
        attn_stats<<<dim3(4 * 64 * 4), dim3(256), 0, stream>>>(K, Q, pb, 8);
        repack3<<<dim3(4 * 128), dim3(256), 0, stream>>>(K, V, ws);
        attn_mf2<<<dim3(1024), dim3(256), 0, stream>>>(ws, Q, out, out, 1);
    } else {
        attn_stats<<<dim3(4 * 64 * 4), dim3(256), 0, stream>>>(K, Q, attn, NSEQ);
        attn_final_fb<<<dim3(4 * 64), dim3(512), 0, stream>>>(K, Q, V, out);
    }
}